// Round 1
// baseline (124.404 us; speedup 1.0000x reference)
//
#include <hip/hip_runtime.h>

#define NN 1024
#define NITER 10
#define LLRMAX 19.3f
#define BSZ 512
#define KOUT 960

// boxplus exactly as reference: clip both args, log(1+e^(x+y)) - log(e^x+e^y).
// Computed as log(1 + ex*ey) - log(ex + ey); all intermediates fit fp32
// (max exp arg 19.3 -> e^19.3 ~ 2.4e8, product ~ 5.9e16).
__device__ __forceinline__ float boxp(float x, float y) {
    x = fminf(fmaxf(x, -LLRMAX), LLRMAX);   // v_med3
    y = fminf(fmaxf(y, -LLRMAX), LLRMAX);
    float ex = __expf(x);
    float ey = __expf(y);
    return __logf(1.0f + ex * ey) - __logf(ex + ey);
}

// Packed R storage (r[s] is exactly zero outside these supports — provable
// from msg_r_in sparsity + boxplus(0,y)==0):
//   r[s], s=1..6 : offset (s-1)*64, size 64
//   r[7]         : offset 384,      size 128
//   r[8]         : offset 512,      size 256
//   r[9]         : offset 768,      size 512
__device__ __forceinline__ float r_load(const float* sR, int s, int pos) {
    int off, sz;
    if (s <= 6)      { off = (s - 1) * 64; sz = 64; }
    else if (s == 7) { off = 384;          sz = 128; }
    else if (s == 8) { off = 512;          sz = 256; }
    else             { off = 768;          sz = 512; }
    return (pos < sz) ? sR[off + pos] : 0.0f;
}

__global__ __launch_bounds__(256, 2) void polar_bp(const float* __restrict__ in,
                                                   float* __restrict__ out) {
    __shared__ float sL[9][NN];    // sL[k] holds L-message stage k+1
    __shared__ float sLLR[NN];     // llr_ch = -input
    __shared__ float sR[1280];     // packed R messages (see r_load)

    const int tid = threadIdx.x;
    const int batch = blockIdx.x;

    // Load llr_ch = -in, one float4 per thread (coalesced 16B/lane).
    {
        const float4* in4 = (const float4*)(in + (size_t)batch * NN);
        float4 v = in4[tid];
        ((float4*)sLLR)[tid] = make_float4(-v.x, -v.y, -v.z, -v.w);
    }
    // msg_l starts at zero.
    #pragma unroll
    for (int i = 0; i < 9 * NN / 256; ++i)
        (&sL[0][0])[tid + i * 256] = 0.0f;
    __syncthreads();

    for (int it = 0; it < NITER; ++it) {
        // ---------------- forward: R messages (sparse support) ----------------
        // Stages 0..5 touch only positions 0..63 -> wave 0 in registers,
        // butterfly exchange via shfl_xor. r[0][0..63] = LLRMAX (frozen set).
        if (tid < 64) {
            float r = LLRMAX;
            #pragma unroll
            for (int s = 0; s <= 5; ++s) {
                float l  = sL[s][tid];                 // L[s+1][j], stable during fwd
                float rp = __shfl_xor(r, 1 << s, 64);
                float lp = __shfl_xor(l, 1 << s, 64);
                bool isB = (tid >> s) & 1;
                // a-lane: boxp(r_a, l_b + r_b);  b-lane: boxp(r_a, l_a) + r_b
                r = isB ? (boxp(rp, lp) + r) : boxp(r, lp + rp);
                sR[s * 64 + tid] = r;                  // store r[s+1][j]
            }
            // stage 6: a=j, b=j+64; r[6][b]=0
            float l1 = sL[6][tid], l2 = sL[6][tid + 64];
            sR[384 + tid]      = boxp(r, l2);          // r[7][a]
            sR[384 + 64 + tid] = boxp(r, l1);          // r[7][b]
        }
        __syncthreads();
        // stage 7: pairs p<128: a=p, b=p+128; r[7][b]=0
        if (tid < 128) {
            float l1 = sL[7][tid], l2 = sL[7][tid + 128];
            float r1 = sR[384 + tid];
            sR[512 + tid]       = boxp(r1, l2);
            sR[512 + 128 + tid] = boxp(r1, l1);
        }
        __syncthreads();
        // stage 8: pairs p<256 (all threads): a=p, b=p+256; r[8][b]=0
        {
            float l1 = sL[8][tid], l2 = sL[8][tid + 256];
            float r1 = sR[512 + tid];
            sR[768 + tid]       = boxp(r1, l2);
            sR[768 + 256 + tid] = boxp(r1, l1);
        }
        __syncthreads();
        // forward stage 9 skipped: r_msgs[10] is never consumed.

        // ---------------- backward: L messages, stages 9..1 ----------------
        #pragma unroll
        for (int s = 9; s >= 1; --s) {
            #pragma unroll
            for (int pp = 0; pp < 2; ++pp) {
                int p  = tid + pp * 256;
                int q  = p >> s;
                int rr = p & ((1 << s) - 1);
                int a  = (q << (s + 1)) | rr;
                int b  = a | (1 << s);
                float l1 = (s == 9) ? sLLR[a] : sL[s][a];
                float l2 = (s == 9) ? sLLR[b] : sL[s][b];
                float r1 = r_load(sR, s, a);
                float r2 = r_load(sR, s, b);
                sL[s - 1][a] = boxp(l1, l2 + r2);      // l1_out
                sL[s - 1][b] = boxp(r1, l1) + l2;      // l2_out
            }
            __syncthreads();
        }
        // backward stage 0 deferred: l_msgs[0] feeds nothing until output.
    }

    // Final backward stage 0 -> output. Only info positions (>=64) matter;
    // for pairs p>=32: r1=r2=0 exactly, so out_a=-boxp(l1,l2), out_b=-l2.
    #pragma unroll
    for (int pp = 0; pp < 2; ++pp) {
        int p = tid + pp * 256;
        if (p >= 32) {
            int a = 2 * p, b = a + 1;
            float l1 = sL[0][a], l2 = sL[0][b];
            out[(size_t)batch * KOUT + (a - 64)] = -boxp(l1, l2);
            out[(size_t)batch * KOUT + (b - 64)] = -l2;
        }
    }
}

extern "C" void kernel_launch(void* const* d_in, const int* in_sizes, int n_in,
                              void* d_out, int out_size, void* d_ws, size_t ws_size,
                              hipStream_t stream) {
    const float* in = (const float*)d_in[0];
    float* out = (float*)d_out;
    polar_bp<<<BSZ, 256, 0, stream>>>(in, out);
}

// Round 2
// 104.608 us; speedup vs baseline: 1.1892x; 1.1892x over previous
//
#include <hip/hip_runtime.h>

#define LLRMAX 19.3f
#define BSZ 512
#define KOUT 960

// boxplus exactly as reference: clip both args, log(1+e^(x+y)) - log(e^x+e^y).
// boxp(0,y) == 0 exactly (log(1+ey) - log(1+ey)) -- used to fold zero-R terms
// branchlessly.
__device__ __forceinline__ float boxp(float x, float y) {
    x = fminf(fmaxf(x, -LLRMAX), LLRMAX);   // v_med3
    y = fminf(fmaxf(y, -LLRMAX), LLRMAX);
    float ex = __expf(x);
    float ey = __expf(y);
    return __logf(1.0f + ex * ey) - __logf(ex + ey);
}

// Layout: position p = j*256 + tid, j = 0..3 held in registers per thread.
//   stage s=0..5 : pair distance 2^s  -> lane xor      -> __shfl_xor
//   stage s=6    : tid ^ 64           -> wave0<->1, 2<->3 -> LDS exchange
//   stage s=7    : tid ^ 128          -> waves01<->23     -> LDS exchange
//   stage s=8,9  : j ^ 1, j ^ 2       -> intra-lane       -> free
// R-message sparse supports (provable: msg_r_in zero outside frozen set +
// boxp(0,y)==0):  r[1..6]: p<64 (wave0)   r[7]: p<128   r[8]: p<256
//                 r[9]: p<512 (j=0,1)     fwd stage 9 output never consumed.
// L-message supports needed by next forward: L[1..6]: p<64, L[7]: p<128,
// L[8]: p<256, L[9]: p<512. All held in registers.
__global__ __launch_bounds__(256, 2) void polar_bp(const float* __restrict__ in,
                                                   float* __restrict__ out) {
    __shared__ float xb7L[4][256];   // bwd stage 7 L exchange
    __shared__ float xb6L[4][256];   // bwd stage 6 L exchange (separate -> no extra barrier)
    __shared__ float xbR7b[128];     // bwd stage 7 r[7]
    __shared__ float xbR6b[64];      // bwd stage 6 r[6]
    __shared__ float f6L[128];       // fwd stage 6 L[7]
    __shared__ float f6R[64];        // fwd stage 6 r[6]
    __shared__ float f7L[256];       // fwd stage 7 L[8]
    __shared__ float f7R[128];       // fwd stage 7 r[7]

    const int tid = threadIdx.x;
    const int w = tid >> 6;
    const int batch = blockIdx.x;

    // llr_ch = -in, strided register layout
    float llr[4];
    const float* inb = in + (size_t)batch * 1024;
#pragma unroll
    for (int j = 0; j < 4; ++j) llr[j] = -inb[j * 256 + tid];

    float Lc[4] = {0.f, 0.f, 0.f, 0.f};
    float Ls9[2] = {0.f, 0.f};                    // L[9] at j=0,1 (p<512)
    float Ls8 = 0.f;                              // L[8] at j=0   (p<256)
    float Ls7 = 0.f;                              // L[7] at j=0, tid<128
    float Ls[7] = {0.f, 0.f, 0.f, 0.f, 0.f, 0.f, 0.f};  // Ls[1..6]: L[s] p<64 (wave0)
    float Rs[7] = {0.f, 0.f, 0.f, 0.f, 0.f, 0.f, 0.f};  // r[1..6] p<64 (wave0)
    float Rs7 = 0.f, Rs8 = 0.f, Rs9[2] = {0.f, 0.f};

    for (int it = 0; it < 10; ++it) {
        // ---- forward: R messages over sparse support ----
        if (w == 0) {                              // stages 0..5, shuffle chain
            float r = LLRMAX;                      // r[0] on frozen set
#pragma unroll
            for (int s = 0; s <= 5; ++s) {
                float lp = __shfl_xor(Ls[s + 1], 1 << s, 64);
                float rp = __shfl_xor(r, 1 << s, 64);
                bool isB = (tid >> s) & 1;
                float x = isB ? rp : r;            // a: boxp(r, lp+rp); b: boxp(rp, lp)+r
                float y = isB ? lp : lp + rp;
                float c = boxp(x, y);
                r = isB ? c + r : c;
                Rs[s + 1] = r;
            }
        }
        // stage 6: wave0 <-> wave1 (r2 = 0 on b-side)
        if (tid < 128) f6L[tid] = Ls7;
        if (tid < 64)  f6R[tid] = Rs[6];
        __syncthreads();                           // B1
        if (tid < 64)       Rs7 = boxp(Rs[6], f6L[tid + 64]);
        else if (tid < 128) Rs7 = boxp(f6R[tid - 64], f6L[tid - 64]);
        // stage 7: waves01 <-> waves23
        f7L[tid] = Ls8;
        if (tid < 128) f7R[tid] = Rs7;
        __syncthreads();                           // B2
        if (tid < 128) Rs8 = boxp(Rs7, f7L[tid + 128]);
        else           Rs8 = boxp(f7R[tid - 128], f7L[tid - 128]);
        // stage 8: intra-lane (j=0 <-> j=1), r2 = 0
        Rs9[0] = boxp(Rs8, Ls9[1]);
        Rs9[1] = boxp(Rs8, Ls9[0]);
        // fwd stage 9 skipped: r[10] never consumed.

        // ---- backward: L messages ----
        // stage 9: pairs (j, j+2) intra-lane; l_in = llr; r2 = 0
        {
            float n0 = boxp(llr[0], llr[2]);
            float n1 = boxp(llr[1], llr[3]);
            float n2 = boxp(Rs9[0], llr[0]) + llr[2];
            float n3 = boxp(Rs9[1], llr[1]) + llr[3];
            Lc[0] = n0; Lc[1] = n1; Lc[2] = n2; Lc[3] = n3;
            Ls9[0] = n0; Ls9[1] = n1;
        }
        // stage 8: pairs (j0,j1), (j2,j3) intra-lane; r only at j=0 (p<256)
        {
            float a0 = boxp(Lc[0], Lc[1]);
            float b0 = boxp(Rs8, Lc[0]) + Lc[1];
            float a2 = boxp(Lc[2], Lc[3]);
            float b2 = Lc[3];                      // boxp(0, l1) + l2
            Lc[0] = a0; Lc[1] = b0; Lc[2] = a2; Lc[3] = b2;
            Ls8 = Lc[0];
        }
        // stage 7: tid ^ 128 cross-wave; r[7] only feeds b-side j=0
#pragma unroll
        for (int j = 0; j < 4; ++j) xb7L[j][tid] = Lc[j];
        if (tid < 128) xbR7b[tid] = Rs7;
        __syncthreads();                           // B3
        if (tid < 128) {                           // a-side: r2 = 0 all j
#pragma unroll
            for (int j = 0; j < 4; ++j) Lc[j] = boxp(Lc[j], xb7L[j][tid + 128]);
        } else {                                   // b-side: only j=0 has r1 != 0
            Lc[0] = boxp(xbR7b[tid - 128], xb7L[0][tid - 128]) + Lc[0];
        }
        Ls7 = Lc[0];
        // stage 6: tid ^ 64 cross-wave; r[6] only feeds b-side j=0 wave1
#pragma unroll
        for (int j = 0; j < 4; ++j) xb6L[j][tid] = Lc[j];
        if (tid < 64) xbR6b[tid] = Rs[6];
        __syncthreads();                           // B4
        if ((tid & 64) == 0) {                     // waves 0,2: a-side, r2 = 0
#pragma unroll
            for (int j = 0; j < 4; ++j) Lc[j] = boxp(Lc[j], xb6L[j][tid + 64]);
        } else if (tid < 128) {                    // wave 1: b-side j=0
            Lc[0] = boxp(xbR6b[tid - 64], xb6L[0][tid - 64]) + Lc[0];
        }                                          // wave 3: unchanged (r1 = 0)
        Ls[6] = Lc[0];
        // stages 5..1: intra-wave shuffles; r terms zero except wave0 j=0
#pragma unroll
        for (int s = 5; s >= 1; --s) {
            const int m = 1 << s;
            float rv = (w == 0) ? Rs[s] : 0.0f;    // wave-uniform select
            float rp = __shfl_xor(rv, m, 64);
            float lp0 = __shfl_xor(Lc[0], m, 64);
            float lp1 = __shfl_xor(Lc[1], m, 64);
            float lp2 = __shfl_xor(Lc[2], m, 64);
            float lp3 = __shfl_xor(Lc[3], m, 64);
            bool isB = (tid >> s) & 1;
            // j=0: a: boxp(l1, lp+rp); b: boxp(rp, lp) + l2  (rp==0 -> exact no-op)
            float x = isB ? rp : Lc[0];
            float y = isB ? lp0 : lp0 + rp;
            float c = boxp(x, y);
            Lc[0] = isB ? c + Lc[0] : c;
            // j>0: r = 0 -> b-side unchanged, a-side boxp(own, partner)
            float c1 = boxp(Lc[1], lp1); Lc[1] = isB ? Lc[1] : c1;
            float c2 = boxp(Lc[2], lp2); Lc[2] = isB ? Lc[2] : c2;
            float c3 = boxp(Lc[3], lp3); Lc[3] = isB ? Lc[3] : c3;
            Ls[s] = Lc[0];
        }
        // stage 0 deferred: l_msgs[0] only feeds the output.
    }

    // Final stage 0 -> output. Output positions p>=64 all have r1=r2=0:
    // even p: -boxp(l1, l2); odd p: -l2.
    const size_t ob = (size_t)batch * KOUT;
#pragma unroll
    for (int j = 0; j < 4; ++j) {
        float lp = __shfl_xor(Lc[j], 1, 64);
        bool odd = tid & 1;
        float o = odd ? -Lc[j] : -boxp(Lc[j], lp);
        int p = j * 256 + tid;
        if (p >= 64) out[ob + p - 64] = o;
    }
}

extern "C" void kernel_launch(void* const* d_in, const int* in_sizes, int n_in,
                              void* d_out, int out_size, void* d_ws, size_t ws_size,
                              hipStream_t stream) {
    const float* in = (const float*)d_in[0];
    float* out = (float*)d_out;
    polar_bp<<<BSZ, 256, 0, stream>>>(in, out);
}